// Round 4
// baseline (165.709 us; speedup 1.0000x reference)
//
#include <hip/hip_runtime.h>
#include <hip/hip_bf16.h>
#include <math.h>

// Problem shape (fixed): x [B,T,D] fp32, log_alpha scalar fp32, out [B,T,D] fp32.
#define B_ 4
#define T_ 4096
#define D_ 512
#define BT 128                 // t/s tile size
#define BK 32                  // K per pipeline step
#define STEPS (D_ / BK)        // 16
#define NT (T_ / BT)           // 32 tiles per batch
#define NPAIR (NT * (NT + 1) / 2)  // 528 lower-triangle tile pairs

// Workspace layout (needs 64 KiB + 16 MiB):
//   [0 .. 64KiB)                maxsim as order-preserving uint32 [B*T]
//   [64KiB .. 64KiB+B*T*D*2)    xn: normalized rows, bf16 bits (ushort)

typedef short bf16x8 __attribute__((ext_vector_type(8)));
typedef float f32x4 __attribute__((ext_vector_type(4)));

__device__ __forceinline__ unsigned short f2bf(float f) {
    unsigned u = __float_as_uint(f);
    u += 0x7FFFu + ((u >> 16) & 1u);   // RNE
    return (unsigned short)(u >> 16);
}
// monotone float -> uint so unsigned atomicMax orders like float
__device__ __forceinline__ unsigned f2ord(float f) {
    unsigned u = __float_as_uint(f);
    return (u & 0x80000000u) ? ~u : (u | 0x80000000u);
}
__device__ __forceinline__ float ord2f(unsigned u) {
    unsigned b = (u & 0x80000000u) ? (u ^ 0x80000000u) : ~u;
    return __uint_as_float(b);
}

// lgkm-only barrier: flush LDS ops + s_barrier, but let global loads stay
// in flight (vmcnt NOT drained — this is the whole point of the pipeline).
// simm16: vmcnt[3:0]=15 | expcnt=7<<4 | lgkmcnt=0<<8 | vmcnt[5:4]=3<<14
__device__ __forceinline__ void barrier_lgkm_only() {
    __builtin_amdgcn_s_waitcnt(0xC07F);
    __builtin_amdgcn_s_barrier();
}

// ---- Kernel 1: one wave per row. inv-norm + bf16 row write + maxsim init ----
__global__ __launch_bounds__(256) void k_norm(const float* __restrict__ x,
                                              unsigned short* __restrict__ xn,
                                              unsigned* __restrict__ maxsim) {
    int w = (blockIdx.x * 256 + threadIdx.x) >> 6;   // row id (B*T rows)
    int lane = threadIdx.x & 63;
    const float4* xr = (const float4*)(x + (size_t)w * D_);
    float4 a = xr[lane];          // lane-contiguous: full coalescing
    float4 b = xr[lane + 64];
    float ss = a.x * a.x + a.y * a.y + a.z * a.z + a.w * a.w +
               b.x * b.x + b.y * b.y + b.z * b.z + b.w * b.w;
#pragma unroll
    for (int off = 32; off > 0; off >>= 1) ss += __shfl_xor(ss, off);
    float inv = 1.0f / fmaxf(sqrtf(ss), 1e-12f);
    unsigned u0 = (unsigned)f2bf(a.x * inv) | ((unsigned)f2bf(a.y * inv) << 16);
    unsigned u1 = (unsigned)f2bf(a.z * inv) | ((unsigned)f2bf(a.w * inv) << 16);
    unsigned u2 = (unsigned)f2bf(b.x * inv) | ((unsigned)f2bf(b.y * inv) << 16);
    unsigned u3 = (unsigned)f2bf(b.z * inv) | ((unsigned)f2bf(b.w * inv) << 16);
    uint2* xo = (uint2*)(xn + (size_t)w * D_);
    xo[lane]      = make_uint2(u0, u1);
    xo[lane + 64] = make_uint2(u2, u3);
    if (lane == 0) maxsim[w] = f2ord(-2.0f);
}

// ---- Kernel 2: one block per (t-tile, s-tile) pair, register-staged pipeline ----
// LDS: 2 ping-pong buffers, each 256 rows (A:0-127, B:128-255) x 32 elems.
// XOR swizzle (R2-verified zero-conflict): chunk q of row r lives at
// position q ^ ((r>>1)&3). Hoisted on both write and read sides.
// NOTE: plain launch_bounds(256) — (256,4) spilled in R2. Do not re-add.
__global__ __launch_bounds__(256) void k_maxsim(const unsigned short* __restrict__ xn,
                                                unsigned* __restrict__ maxsim) {
    __shared__ __align__(16) unsigned short Buf[2][256 * BK];
    const int b = blockIdx.y;
    const int p = blockIdx.x;
    // triangular decode p -> (ti, si), si <= ti
    int ti = (int)((sqrtf(8.0f * (float)p + 1.0f) - 1.0f) * 0.5f);
    while ((ti + 1) * (ti + 2) / 2 <= p) ti++;
    while (ti * (ti + 1) / 2 > p) ti--;
    const int si = p - ti * (ti + 1) / 2;
    const int t0 = ti * BT, s0 = si * BT;

    const int tid = threadIdx.x;
    const int wave = tid >> 6, lane = tid & 63;
    const int wm = wave >> 1, wn = wave & 1;     // 2x2 waves -> 64x64 each
    const int qa = lane >> 4, la = lane & 15;
    const int swz = (la >> 1) & 3;               // read-side row-phase XOR

    const unsigned short* Ab = xn + (size_t)(b * T_ + t0) * D_;
    const unsigned short* Bb = xn + (size_t)(b * T_ + s0) * D_;

    // per-thread staging: 4 x 16B chunks per step (2 A rows, 2 B rows)
    const int srow = tid >> 2;                   // 0..63
    const int sq = tid & 3;
    const unsigned short* gA0 = Ab + (size_t)srow * D_ + sq * 8;
    const unsigned short* gA1 = gA0 + (size_t)64 * D_;
    const unsigned short* gB0 = Bb + (size_t)srow * D_ + sq * 8;
    const unsigned short* gB1 = gB0 + (size_t)64 * D_;
    const int wpos = (sq ^ ((srow >> 1) & 3)) * 8;   // same phase for srow, srow+64(+128,+192)
    const int wo0 = (srow) * BK + wpos;
    const int wo1 = (srow + 64) * BK + wpos;
    const int wo2 = (srow + 128) * BK + wpos;
    const int wo3 = (srow + 192) * BK + wpos;

    f32x4 acc[4][4];
#pragma unroll
    for (int i = 0; i < 4; i++)
#pragma unroll
        for (int j = 0; j < 4; j++) acc[i][j] = (f32x4){0.f, 0.f, 0.f, 0.f};

    // ---- pipeline prologue: step0 -> LDS buf0, step1 -> regs ----
    uint4 r0 = *(const uint4*)(gA0);
    uint4 r1 = *(const uint4*)(gA1);
    uint4 r2 = *(const uint4*)(gB0);
    uint4 r3 = *(const uint4*)(gB1);
    {
        unsigned short* b0 = &Buf[0][0];
        *(uint4*)&b0[wo0] = r0;       // auto vmcnt wait (prologue only)
        *(uint4*)&b0[wo1] = r1;
        *(uint4*)&b0[wo2] = r2;
        *(uint4*)&b0[wo3] = r3;
    }
    r0 = *(const uint4*)(gA0 + BK);
    r1 = *(const uint4*)(gA1 + BK);
    r2 = *(const uint4*)(gB0 + BK);
    r3 = *(const uint4*)(gB1 + BK);

#pragma unroll 2
    for (int k = 0; k < STEPS; ++k) {
        unsigned short* cur = &Buf[k & 1][0];
        unsigned short* nxt = &Buf[(k + 1) & 1][0];
        barrier_lgkm_only();    // step-k data visible; k+2 loads stay in flight

        // prefetch step k+2 (clamped; redundant loads harmless)
        const int ko = (k + 2 < STEPS ? k + 2 : STEPS - 1) * BK;
        uint4 n0 = *(const uint4*)(gA0 + ko);
        uint4 n1 = *(const uint4*)(gA1 + ko);
        uint4 n2 = *(const uint4*)(gB0 + ko);
        uint4 n3 = *(const uint4*)(gB1 + ko);

        // fragments for step k
        bf16x8 af[4], bfr[4];
#pragma unroll
        for (int i = 0; i < 4; i++)
            af[i] = *(const bf16x8*)&cur[(wm * 64 + i * 16 + la) * BK + (qa ^ swz) * 8];
#pragma unroll
        for (int j = 0; j < 4; j++)
            bfr[j] = *(const bf16x8*)&cur[(128 + wn * 64 + j * 16 + la) * BK + (qa ^ swz) * 8];

        // commit step k+1 regs into the other buffer (compiler waits vmcnt(4):
        // k+1's loads are a full step old -> near-free; k+2's stay in flight)
        *(uint4*)&nxt[wo0] = r0;
        *(uint4*)&nxt[wo1] = r1;
        *(uint4*)&nxt[wo2] = r2;
        *(uint4*)&nxt[wo3] = r3;
        r0 = n0; r1 = n1; r2 = n2; r3 = n3;

#pragma unroll
        for (int i = 0; i < 4; i++)
#pragma unroll
            for (int j = 0; j < 4; j++)
                acc[i][j] = __builtin_amdgcn_mfma_f32_16x16x32_bf16(af[i], bfr[j], acc[i][j], 0, 0, 0);
    }

    // epilogue: per-row max over this tile's s-columns, then global atomicMax.
    // C/D layout (verified): col = lane&15, row = (lane>>4)*4 + reg
    const bool diag = (ti == si);
#pragma unroll
    for (int i = 0; i < 4; i++) {
#pragma unroll
        for (int r = 0; r < 4; r++) {
            int tl = wm * 64 + i * 16 + qa * 4 + r;   // local t row
            float m = -2.0f;
#pragma unroll
            for (int j = 0; j < 4; j++) {
                int sl = wn * 64 + j * 16 + la;       // local s col
                float v = acc[i][j][r];
                if (!diag || sl < tl) m = fmaxf(m, v);
            }
#pragma unroll
            for (int off = 1; off < 16; off <<= 1) m = fmaxf(m, __shfl_xor(m, off));
            if (la == 0) atomicMax(&maxsim[b * T_ + t0 + tl], f2ord(m));
        }
    }
}

// ---- Kernel 3: gate + tanh-GELU, one float4 per thread ----
__device__ __forceinline__ float gelu_tanh(float y) {
    float t = tanhf(0.7978845608028654f * (y + 0.044715f * y * y * y));
    return 0.5f * y * (1.0f + t);
}

__global__ __launch_bounds__(256) void k_gate(const float* __restrict__ x,
                                              const float* __restrict__ log_alpha,
                                              const unsigned* __restrict__ maxsim,
                                              float* __restrict__ out) {
    int idx = blockIdx.x * 256 + threadIdx.x;     // one float4 per thread
    float la = log_alpha[0];
    float alpha = (la > 20.0f) ? la : log1pf(expf(la));
    int row = idx >> 7;                           // 128 float4-threads per row
    float m = fmaxf(ord2f(maxsim[row]), -1.0f);
    float novelty = 1.0f - (m + 1.0f) * 0.5f;
    float gate = 1.0f + alpha * novelty;
    float4 v = ((const float4*)x)[idx];
    float4 o;
    o.x = gelu_tanh(v.x * gate);
    o.y = gelu_tanh(v.y * gate);
    o.z = gelu_tanh(v.z * gate);
    o.w = gelu_tanh(v.w * gate);
    ((float4*)out)[idx] = o;
}

extern "C" void kernel_launch(void* const* d_in, const int* in_sizes, int n_in,
                              void* d_out, int out_size, void* d_ws, size_t ws_size,
                              hipStream_t stream) {
    const float* x = (const float*)d_in[0];
    const float* log_alpha = (const float*)d_in[1];
    float* out = (float*)d_out;

    unsigned* maxsim = (unsigned*)d_ws;
    unsigned short* xn = (unsigned short*)((char*)d_ws + 65536);

    const int rows = B_ * T_;                     // 16384
    k_norm<<<rows / 4, 256, 0, stream>>>(x, xn, maxsim);

    dim3 g2(NPAIR, B_);
    k_maxsim<<<g2, 256, 0, stream>>>(xn, maxsim);

    k_gate<<<(B_ * T_ * D_ / 4) / 256, 256, 0, stream>>>(x, log_alpha, maxsim, out);
}